// Round 2
// baseline (119.391 us; speedup 1.0000x reference)
//
#include <hip/hip_runtime.h>

// Pendulum 1-DOF Hamiltonian dynamics, analytic closed form:
//   out[i,0] = p                  (= y[i,1])
//   out[i,1] = -G * sin(theta)    (theta = y[i,0]), G = 9.81
//
// y is [B,2] f32 row-major (interleaved theta,p). One 16B vector per lane
// covers 2 rows: load (t0,p0,t1,p1) -> store (p0,-G sin t0, p1,-G sin t1).
// Pure streaming (no reuse): nontemporal load/store, exact grid, __sinf.

typedef float f4 __attribute__((ext_vector_type(4)));

__global__ __launch_bounds__(256) void pend1dof_kernel(
    const f4* __restrict__ y4, f4* __restrict__ out4, int n4) {
    const float G = 9.81f;
    int i = blockIdx.x * 256 + threadIdx.x;
    if (i < n4) {
        f4 v = __builtin_nontemporal_load(&y4[i]);
        f4 r;
        r.x = v.y;
        r.y = -G * __sinf(v.x);
        r.z = v.w;
        r.w = -G * __sinf(v.z);
        __builtin_nontemporal_store(r, &out4[i]);
    }
}

extern "C" void kernel_launch(void* const* d_in, const int* in_sizes, int n_in,
                              void* d_out, int out_size, void* d_ws, size_t ws_size,
                              hipStream_t stream) {
    // inputs: d_in[0] = t (1 elem, unused), d_in[1] = y ([B,2] f32)
    const f4* y4 = (const f4*)d_in[1];
    f4* out4 = (f4*)d_out;
    int n_elems = in_sizes[1];            // B*2 floats (B = 8388608 -> 16777216)
    int n4 = n_elems / 4;                 // 4194304 float4s

    const int block = 256;
    int blocks = (n4 + block - 1) / block;  // 16384 blocks, one f4 per lane

    pend1dof_kernel<<<blocks, block, 0, stream>>>(y4, out4, n4);
}